// Round 7
// baseline (233.878 us; speedup 1.0000x reference)
//
#include <hip/hip_runtime.h>

// CrossAttention fused kernel for MI355X (gfx950) — R21
// R21 = R19 with P1/P3 wave geometry 64x64 -> 32x128 (LDS-sum cut):
//  - R20 post-mortem: sum-of-pipes model. Halving L2 weights while doubling
//    LDS reads = net 0 (185 vs 183). Pipes/CU: L2 125K, VALU 93K, LDS 82K,
//    MFMA 76K cyc of 444K total -> serial phases make time ~= SUM(pipes).
//  - P1/P3: wave (rg=wv>>2, cg=wv&3) computes 32 rows x 128 cols: per K-slice
//    1 A-frag LDS read : 4 MFMA32 (was 2:4) -> P1/P3 LDS traffic halves.
//    acc = 4 x f32x16 = 64 AGPR (unchanged); weights 2-deep x 4-tile ping-pong
//    (32 VGPR, unchanged); weight traffic back to R19 level (L2-free per R20).
//  - P2: R19 per-ks PV, setprio hoisted out of ks loop (R18 placement).
//  - extra __syncthreads after q writeback (q cols now cross-wave).

#define DQ 512
#define DC 768
#define MCTX 77
#define MPAD 96
#define DH 64

typedef __attribute__((ext_vector_type(8))) short bf16x8;
typedef __attribute__((ext_vector_type(4))) short s16x4;
typedef __attribute__((ext_vector_type(4))) float f32x4;
typedef __attribute__((ext_vector_type(16))) float f32x16;

__device__ __forceinline__ short f2bf(float f) {
    unsigned u = __builtin_bit_cast(unsigned, f);
    u = (u + 0x7FFFu + ((u >> 16) & 1u)) >> 16;
    return (short)u;
}
// packed f32 pair -> bf16 pair (lo in bits[15:0]); RTNE, single VALU op
__device__ __forceinline__ unsigned cvtpk(float lo, float hi) {
    unsigned r;
    asm("v_cvt_pk_bf16_f32 %0, %1, %2" : "=v"(r) : "v"(lo), "v"(hi));
    return r;
}

#define SWZ(row, byte) ((byte) ^ (((row) & 7) << 4))
#define MFMA(a, b, c) __builtin_amdgcn_mfma_f32_16x16x32_bf16((a), (b), (c), 0, 0, 0)
#define MFMA32(a, b, c) __builtin_amdgcn_mfma_f32_32x32x16_bf16((a), (b), (c), 0, 0, 0)

// ---------------------------------------------------------------------------
// Fused weight prep (one launch):
//   blocks 0..127   : pack Wq -> WqF   (32x32x16-frag flat)
//   blocks 128..255 : pack Wo -> WoF
//   blocks 256..639 : transpose+cast Wk -> WkT [512][768]
//   blocks 640..1023: transpose+cast Wv -> WvT
// ---------------------------------------------------------------------------
__global__ void prep_weights(const float* __restrict__ Wq, const float* __restrict__ Wk,
                             const float* __restrict__ Wv, const float* __restrict__ Wo,
                             short* __restrict__ WqF, short* __restrict__ WkT,
                             short* __restrict__ WvT, short* __restrict__ WoF) {
    __shared__ float t[32][33];
    int bid = blockIdx.x;
    if (bid < 256) {
        // ---- pack_frag32: K=512, N=512 ----
        const float* src = (bid < 128) ? Wq : Wo;
        short* dst = (bid < 128) ? WqF : WoF;
        int vb = bid & 127;
        int idx = vb * 256 + threadIdx.x;
        int lane = idx & 63;
        int chunk = idx >> 6;
        int tt = chunk % 16, ks = chunk / 16;  // NT = 512>>5 = 16
        int n = tt * 32 + (lane & 31);
        int k0 = ks * 16 + (lane >> 5) * 8;
        bf16x8 v;
#pragma unroll
        for (int j = 0; j < 8; ++j) v[j] = f2bf(src[(size_t)(k0 + j) * 512 + n]);
        *(bf16x8*)(dst + (size_t)idx * 8) = v;
    } else {
        // ---- transpose_cast: K=768, N=512 ----
        const float* src = (bid < 640) ? Wk : Wv;
        short* dst = (bid < 640) ? WkT : WvT;
        int vb = (bid - 256) % 384;
        int tn = vb % 16, tk = vb / 16;  // ntn = 512>>5 = 16
        int tx = threadIdx.x & 31, ty = threadIdx.x >> 5;
#pragma unroll
        for (int i = 0; i < 32; i += 8)
            t[ty + i][tx] = src[(size_t)(tk * 32 + ty + i) * 512 + tn * 32 + tx];
        __syncthreads();
#pragma unroll
        for (int i = 0; i < 32; i += 8)
            dst[(size_t)(tn * 32 + ty + i) * 768 + tk * 32 + tx] = f2bf(t[tx][ty + i]);
    }
}

// ---------------------------------------------------------------------------
// K: Kb [16][96][512] ([b][ctx][dim], rows 77..95 zero)
// V: VbT [16][512][96] ([b][dim][ctx], ctx 77..95 zero)
// ---------------------------------------------------------------------------
__global__ __launch_bounds__(256, 1) void kv_proj(const float* __restrict__ ctxin,
                                                  const short* __restrict__ WkT,
                                                  const short* __restrict__ WvT,
                                                  short* __restrict__ Kb,
                                                  short* __restrict__ VbT) {
    int b = blockIdx.x >> 2;
    int kv = (blockIdx.x >> 1) & 1;
    int half = blockIdx.x & 1;
    const short* WT = kv ? WvT : WkT;

    __shared__ short A[48 * 768];
    const int tid = threadIdx.x;
    const int lane = tid & 63, wv = tid >> 6;
    const int l15 = lane & 15, l4 = lane >> 4;

#pragma unroll
    for (int it = 0; it < 36; ++it) {
        int id = it * 256 + tid;
        int row = id / 192, col = (id % 192) * 4;
        int gctx = half * 48 + row;
        float4 v = make_float4(0.f, 0.f, 0.f, 0.f);
        if (gctx < MCTX)
            v = ((const float4*)(ctxin + ((size_t)(b * MCTX + gctx)) * DC))[id % 192];
        s16x4 s4;
        s4[0] = f2bf(v.x); s4[1] = f2bf(v.y); s4[2] = f2bf(v.z); s4[3] = f2bf(v.w);
        *(s16x4*)((char*)A + row * 1536 + SWZ(row, col * 2)) = s4;
    }
    __syncthreads();

    f32x4 zf = {0.f, 0.f, 0.f, 0.f};
    f32x4 acc[3][8];
#pragma unroll
    for (int m = 0; m < 3; ++m)
#pragma unroll
        for (int nb = 0; nb < 8; ++nb) acc[m][nb] = zf;

    for (int ks = 0; ks < 24; ++ks) {
        bf16x8 bb[8], aa[3];
#pragma unroll
        for (int nb = 0; nb < 8; ++nb) {
            int n = wv * 128 + nb * 16 + l15;
            bb[nb] = *(const bf16x8*)((const char*)WT + (size_t)n * 1536 + ks * 64 + l4 * 16);
        }
#pragma unroll
        for (int m = 0; m < 3; ++m) {
            int row = m * 16 + l15;
            aa[m] = *(const bf16x8*)((char*)A + row * 1536 + SWZ(row, ks * 64 + l4 * 16));
        }
#pragma unroll
        for (int nb = 0; nb < 8; ++nb)
#pragma unroll
            for (int m = 0; m < 3; ++m) acc[m][nb] = MFMA(aa[m], bb[nb], acc[m][nb]);
    }

    if (kv == 0) {
#pragma unroll
        for (int m = 0; m < 3; ++m)
#pragma unroll
            for (int nb = 0; nb < 8; ++nb)
#pragma unroll
                for (int r = 0; r < 4; ++r) {
                    int ctxi = half * 48 + m * 16 + l4 * 4 + r;
                    int col = wv * 128 + nb * 16 + l15;
                    Kb[((size_t)(b * MPAD + ctxi)) * 512 + col] = f2bf(acc[m][nb][r]);
                }
    } else {
#pragma unroll
        for (int m = 0; m < 3; ++m)
#pragma unroll
            for (int nb = 0; nb < 8; ++nb)
#pragma unroll
                for (int r = 0; r < 4; ++r) {
                    int ctxi = half * 48 + m * 16 + l4 * 4 + r;
                    int col = wv * 128 + nb * 16 + l15;
                    VbT[((size_t)(b * 512 + col)) * MPAD + ctxi] = f2bf(acc[m][nb][r]);
                }
    }
}

// ---------------------------------------------------------------------------
// Fused: LN -> Qproj (32x32, swapped) -> attention (16x16, swapped PV)
//        -> Oproj (32x32, direct) + epilogue
// grid: 1024 blocks (XCD-swizzled), 512 threads (8 waves), 64 rows/block
// P1/P3 wave tile: 32 rows x 128 cols (rg = wv>>2, cg = wv&3)
// ---------------------------------------------------------------------------
__global__ __launch_bounds__(512, 4) void fused_attn(
    const float* __restrict__ x, const float* __restrict__ gamma,
    const float* __restrict__ beta, const short* __restrict__ WqF,
    const short* __restrict__ WoF, const short* __restrict__ Kb,
    const short* __restrict__ VbT, const float* __restrict__ bo,
    float* __restrict__ out) {
    __shared__ short A[64 * 512];  // 64KB: h -> q -> AO, rows 1024B, XOR swizzled

    const int tid = threadIdx.x;
    const int lane = tid & 63, wv = tid >> 6;  // wv: head (P2); (rg,cg) in P1/P3
    const int l15 = lane & 15, l4 = lane >> 4;
    const int l31 = lane & 31, hi5 = lane >> 5;
    const int rg = wv >> 2, cg = wv & 3;
    const int swz = (blockIdx.x & 7) * 128 + (blockIdx.x >> 3);  // XCD-chunked
    const int b = swz >> 6;
    const size_t rowbase = (size_t)swz * 64;

    // ---- Phase 0: LayerNorm -> h bf16 in A (8 rows/wave, 4-row load batches) ----
    {
        float g[8], be[8];
        float4 g0 = ((const float4*)gamma)[lane * 2], g1 = ((const float4*)gamma)[lane * 2 + 1];
        float4 b0 = ((const float4*)beta)[lane * 2], b1 = ((const float4*)beta)[lane * 2 + 1];
        g[0] = g0.x; g[1] = g0.y; g[2] = g0.z; g[3] = g0.w;
        g[4] = g1.x; g[5] = g1.y; g[6] = g1.z; g[7] = g1.w;
        be[0] = b0.x; be[1] = b0.y; be[2] = b0.z; be[3] = b0.w;
        be[4] = b1.x; be[5] = b1.y; be[6] = b1.z; be[7] = b1.w;
#pragma unroll 1
        for (int g4 = 0; g4 < 2; ++g4) {
            float4 v0[4], v1[4];
#pragma unroll
            for (int j = 0; j < 4; ++j) {
                int row = wv * 8 + g4 * 4 + j;
                const float4* xp = (const float4*)(x + (rowbase + row) * DQ);
                v0[j] = xp[lane * 2];
                v1[j] = xp[lane * 2 + 1];
            }
#pragma unroll
            for (int j = 0; j < 4; ++j) {
                int row = wv * 8 + g4 * 4 + j;
                float vv[8] = {v0[j].x, v0[j].y, v0[j].z, v0[j].w,
                               v1[j].x, v1[j].y, v1[j].z, v1[j].w};
                float s = 0.f, s2 = 0.f;
#pragma unroll
                for (int i = 0; i < 8; ++i) { s += vv[i]; s2 = fmaf(vv[i], vv[i], s2); }
#pragma unroll
                for (int m = 1; m < 64; m <<= 1) {
                    s += __shfl_xor(s, m);
                    s2 += __shfl_xor(s2, m);
                }
                float mu = s * (1.f / 512.f);
                float var = s2 * (1.f / 512.f) - mu * mu;
                float rs = rsqrtf(var + 1e-5f);
                float hn[8];
#pragma unroll
                for (int i = 0; i < 8; ++i) hn[i] = (vv[i] - mu) * rs * g[i] + be[i];
                uint4 hv = make_uint4(cvtpk(hn[0], hn[1]), cvtpk(hn[2], hn[3]),
                                      cvtpk(hn[4], hn[5]), cvtpk(hn[6], hn[7]));
                *(uint4*)((char*)A + row * 1024 + SWZ(row, lane * 16)) = hv;
            }
        }
    }

    f32x4 zf = {0.f, 0.f, 0.f, 0.f};

// 4-tile weight load for wave's col group cg (tiles cg*4+tt), K-slice ks
#define LDWF4(dst, W, ks)                                                                  \
    _Pragma("unroll") for (int tt = 0; tt < 4; ++tt) {                                     \
        (dst)[tt] = *(const bf16x8*)((W) +                                                 \
            (size_t)((((ks)*16 + cg * 4 + tt) * 64 + lane)) * 8);                          \
    }
// single A-frag read: row rg*32+l31, k-bytes ks*32 + hi5*16
#define LDT1R(dst, ks)                                                                     \
    {                                                                                      \
        int row_ = rg * 32 + l31;                                                          \
        (dst) = *(const bf16x8*)((char*)A + row_ * 1024 +                                  \
                                 SWZ(row_, (ks)*32 + hi5 * 16));                           \
    }
// K-slice, SWAPPED (phase 1): ACC[ct] += W[ct] * h ; refill W from kk+2
#define GSTEPQ(W, kk)                                                                      \
    {                                                                                      \
        bf16x8 hb;                                                                         \
        LDT1R(hb, (kk));                                                                   \
        _Pragma("unroll") for (int ct = 0; ct < 4; ++ct)                                   \
            qa[ct] = MFMA32((W)[ct], hb, qa[ct]);                                          \
        LDWF4((W), WqF, (kk) + 2);                                                         \
    }
#define GSTEPQ_NR(W, kk)                                                                   \
    {                                                                                      \
        bf16x8 hb;                                                                         \
        LDT1R(hb, (kk));                                                                   \
        _Pragma("unroll") for (int ct = 0; ct < 4; ++ct)                                   \
            qa[ct] = MFMA32((W)[ct], hb, qa[ct]);                                          \
    }
// K-slice, DIRECT (phase 3): ACC[ct] += AO * W[ct] ; refill W from kk+2
#define GSTEPO(W, kk)                                                                      \
    {                                                                                      \
        bf16x8 ab;                                                                         \
        LDT1R(ab, (kk));                                                                   \
        _Pragma("unroll") for (int ct = 0; ct < 4; ++ct)                                   \
            oa[ct] = MFMA32(ab, (W)[ct], oa[ct]);                                          \
        LDWF4((W), WoF, (kk) + 2);                                                         \
    }
#define GSTEPO_NR(W, kk)                                                                   \
    {                                                                                      \
        bf16x8 ab;                                                                         \
        LDT1R(ab, (kk));                                                                   \
        _Pragma("unroll") for (int ct = 0; ct < 4; ++ct)                                   \
            oa[ct] = MFMA32(ab, (W)[ct], oa[ct]);                                          \
    }

    // ---- Phase 1: Q = h @ Wq via swapped 32x32: D = mfma(WqPack, h^T) = q^T ----
    {
        bf16x8 wA[4], wB[4];
        LDWF4(wA, WqF, 0);  // 2-deep x 4-tile ping-pong, issued before barrier
        LDWF4(wB, WqF, 1);
        __syncthreads();   // h complete

        f32x16 qa[4];  // [ct]: wave covers cols cg*128 + ct*32, rows rg*32..+31
#pragma unroll
        for (int ct = 0; ct < 4; ++ct)
#pragma unroll
            for (int i = 0; i < 16; ++i) qa[ct][i] = 0.f;

#pragma unroll 1
        for (int ks = 0; ks < 30; ks += 2) {  // refills cover slices 2..31
            GSTEPQ(wA, ks)
            GSTEPQ(wB, ks + 1)
        }
        GSTEPQ_NR(wA, 30)  // last 2 slices: no refill, no over-read
        GSTEPQ_NR(wB, 31)

        // q writeback (0.125 QK scale folded in): lane = q-row, regs = q-cols
#pragma unroll
        for (int ct = 0; ct < 4; ++ct)
#pragma unroll
            for (int g = 0; g < 4; ++g) {
                uint2 qv = make_uint2(
                    cvtpk(qa[ct][g * 4] * 0.125f, qa[ct][g * 4 + 1] * 0.125f),
                    cvtpk(qa[ct][g * 4 + 2] * 0.125f, qa[ct][g * 4 + 3] * 0.125f));
                int row = rg * 32 + l31;
                int colb = (cg * 128 + ct * 32 + 8 * g + 4 * hi5) * 2;
                *(uint2*)((char*)A + row * 1024 + SWZ(row, colb)) = qv;
            }
        __syncthreads();  // q complete (P2 head cols are cross-wave now)
    }

    // ---- Phase 2: attention for head wv (16x16, swapped PV, P in regs) ----
    {
        const int cb = wv * 64;
        const int srcA = ((l4 & 1) << 5) + l15;
        const int srcB = srcA + 16;
        const bool hi = (l4 >> 1) != 0;

#pragma unroll 1
        for (int rp = 0; rp < 4; ++rp) {
            bf16x8 qf0, qf1;
            {
                int qrow = rp * 16 + l15;
                qf0 = *(const bf16x8*)((char*)A + qrow * 1024 + SWZ(qrow, cb * 2 + l4 * 16));
                qf1 = *(const bf16x8*)((char*)A + qrow * 1024 + SWZ(qrow, cb * 2 + 64 + l4 * 16));
            }
            f32x4 sc[5];
            __builtin_amdgcn_s_setprio(1);
#pragma unroll
            for (int f = 0; f < 5; ++f) {
                bf16x8 k0 = *(const bf16x8*)(Kb + ((size_t)(b * MPAD + f * 16 + l15)) * 512 +
                                             cb + l4 * 8);
                bf16x8 k1 = *(const bf16x8*)(Kb + ((size_t)(b * MPAD + f * 16 + l15)) * 512 +
                                             cb + 32 + l4 * 8);
                sc[f] = MFMA(k0, qf0, zf);
                sc[f] = MFMA(k1, qf1, sc[f]);
            }
            __builtin_amdgcn_s_setprio(0);
            // q was pre-scaled by 0.125 at writeback; scores are final here
            float m = -1e30f;
#pragma unroll
            for (int f = 0; f < 5; ++f)
#pragma unroll
                for (int r = 0; r < 4; ++r) {
                    float v = sc[f][r];
                    if (f == 4 && (64 + l4 * 4 + r) >= MCTX) v = -1e30f;
                    sc[f][r] = v;
                    m = fmaxf(m, v);
                }
            m = fmaxf(m, __shfl_xor(m, 16));
            m = fmaxf(m, __shfl_xor(m, 32));
            float s = 0.f;
#pragma unroll
            for (int f = 0; f < 5; ++f)
#pragma unroll
                for (int r = 0; r < 4; ++r) {
                    float p = __expf(sc[f][r] - m);
                    sc[f][r] = p;
                    s += p;
                }
            s += __shfl_xor(s, 16);
            s += __shfl_xor(s, 32);
            float inv = 1.f / s;
            unsigned pk[6][2];
#pragma unroll
            for (int f = 0; f < 5; ++f) {
                pk[f][0] = cvtpk(sc[f][0] * inv, sc[f][1] * inv);
                pk[f][1] = cvtpk(sc[f][2] * inv, sc[f][3] * inv);
            }
            pk[5][0] = 0; pk[5][1] = 0;

            // PV swapped, per-ks interleave: only 4 pa regs live at a time.
            // D = mfma(A=V^T frag, B=P frag) = (PV)^T
            // lane = q-row (l15), regs r = consecutive dims (nb*16 + l4*4 + r)
            f32x4 ov[4];
#pragma unroll
            for (int nb = 0; nb < 4; ++nb) ov[nb] = zf;
            __builtin_amdgcn_s_setprio(1);
#pragma unroll
            for (int ks = 0; ks < 3; ++ks) {
                unsigned aL0 = __shfl((int)pk[2 * ks][0], srcA);
                unsigned aL1 = __shfl((int)pk[2 * ks][1], srcA);
                unsigned aH0 = __shfl((int)pk[2 * ks + 1][0], srcA);
                unsigned aH1 = __shfl((int)pk[2 * ks + 1][1], srcA);
                unsigned bL0 = __shfl((int)pk[2 * ks][0], srcB);
                unsigned bL1 = __shfl((int)pk[2 * ks][1], srcB);
                unsigned bH0 = __shfl((int)pk[2 * ks + 1][0], srcB);
                unsigned bH1 = __shfl((int)pk[2 * ks + 1][1], srcB);
                unsigned paw[4];
                paw[0] = hi ? aH0 : aL0;
                paw[1] = hi ? aH1 : aL1;
                paw[2] = hi ? bH0 : bL0;
                paw[3] = hi ? bH1 : bL1;
                bf16x8 ap = __builtin_bit_cast(bf16x8, paw);
#pragma unroll
                for (int nb = 0; nb < 4; ++nb) {
                    bf16x8 bv = *(const bf16x8*)(VbT +
                                                 ((size_t)(b * 512 + cb + nb * 16 + l15)) * MPAD +
                                                 ks * 32 + l4 * 8);
                    ov[nb] = MFMA(bv, ap, ov[nb]);  // swapped args
                }
            }
            __builtin_amdgcn_s_setprio(0);
            // AO writeback: vector b64, row = q-row, 4 consecutive dim cols
#pragma unroll
            for (int nb = 0; nb < 4; ++nb) {
                uint2 av = make_uint2(cvtpk(ov[nb][0], ov[nb][1]),
                                      cvtpk(ov[nb][2], ov[nb][3]));
                int row = rp * 16 + l15;
                int colb = (cb + nb * 16 + l4 * 4) * 2;
                *(uint2*)((char*)A + row * 1024 + SWZ(row, colb)) = av;
            }
        }
    }

    // ---- Phase 3: O-proj 32x32 (K=512, direct) + residual + bias ----
    {
        bf16x8 wA[4], wB[4];
        LDWF4(wA, WoF, 0);  // issue before the barrier (global loads, no LDS dep)
        LDWF4(wB, WoF, 1);
        __syncthreads();   // AO complete across all waves

        f32x16 oa[4];  // [ct]: wave covers out cols cg*128 + ct*32, rows rg*32..+31
#pragma unroll
        for (int ct = 0; ct < 4; ++ct)
#pragma unroll
            for (int i = 0; i < 16; ++i) oa[ct][i] = 0.f;

#pragma unroll 1
        for (int ks = 0; ks < 30; ks += 2) {  // refills cover slices 2..31
            GSTEPO(wA, ks)
            GSTEPO(wB, ks + 1)
        }
        GSTEPO_NR(wA, 30)  // last 2 slices: no refill, no over-read
        GSTEPO_NR(wB, 31)

        // epilogue: out = x + oa + bo; lane = out-col (coalesced), regs = rows
#pragma unroll
        for (int ct = 0; ct < 4; ++ct) {
            int col = cg * 128 + ct * 32 + l31;
            float bov = bo[col];
            float xv[16];
#pragma unroll
            for (int rgi = 0; rgi < 16; ++rgi) {
                int row = rg * 32 + (rgi & 3) + 8 * (rgi >> 2) + 4 * hi5;
                xv[rgi] = x[(rowbase + row) * DQ + col];
            }
#pragma unroll
            for (int rgi = 0; rgi < 16; ++rgi) {
                int row = rg * 32 + (rgi & 3) + 8 * (rgi >> 2) + 4 * hi5;
                size_t gi = (rowbase + row) * DQ + col;
                out[gi] = xv[rgi] + oa[ct][rgi] + bov;
            }
        }
    }
}

// ---------------------------------------------------------------------------
extern "C" void kernel_launch(void* const* d_in, const int* in_sizes, int n_in,
                              void* d_out, int out_size, void* d_ws, size_t ws_size,
                              hipStream_t stream) {
    const float* x = (const float*)d_in[0];
    const float* ctx = (const float*)d_in[1];
    const float* gamma = (const float*)d_in[2];
    const float* beta = (const float*)d_in[3];
    const float* Wq = (const float*)d_in[4];
    const float* Wk = (const float*)d_in[5];
    const float* Wv = (const float*)d_in[6];
    const float* Wo = (const float*)d_in[7];
    const float* bo = (const float*)d_in[8];
    float* out = (float*)d_out;

    char* ws = (char*)d_ws;
    short* WqF = (short*)(ws + 0);        // 32x32-frag flat bf16 [32ks][16t][64lane][8]
    short* WkT = (short*)(ws + 524288);   // [512][768] row-major W^T
    short* WvT = (short*)(ws + 1310720);  // [512][768]
    short* WoF = (short*)(ws + 2097152);  // 32x32-frag flat
    short* Kb = (short*)(ws + 2621440);   // [16][96][512]  K: [b][ctx][dim]
    short* VbT = (short*)(ws + 4194304);  // [16][512][96]  V: [b][dim][ctx]

    prep_weights<<<1024, 256, 0, stream>>>(Wq, Wk, Wv, Wo, WqF, WkT, WvT, WoF);
    kv_proj<<<64, 256, 0, stream>>>(ctx, WkT, WvT, Kb, VbT);
    fused_attn<<<1024, 512, 0, stream>>>(x, gamma, beta, WqF, WoF, Kb, VbT, bo, out);
}

// Round 8
// 191.637 us; speedup vs baseline: 1.2204x; 1.2204x over previous
//
#include <hip/hip_runtime.h>

// CrossAttention fused kernel for MI355X (gfx950) — R22
// R22 = R20 (best total, 190.7us) + K-fragment hoist in P2:
//  - R21 post-mortem: wave-tile aspect ratio conserves W-traffic x LDS-reads
//    (R21: W 2x -> +48us/GB marginal; LDS 0.5x -> ~0). 64x64 tile = optimum;
//    that axis is closed. Plateau = L2 issue/latency, all pipes <25%.
//  - P2 QK loop re-issued the same 10 K-frag loads every rp (40/wave vs 10):
//    ~245MB redundant L2 reads + 30 exposed L2 round-trips per wave. R20's P2
//    runs at VGPR 64 of 128 cap -> 40 regs of K fit (R16's V-hoist failed at
//    ~115+48). Hoisted kR[5][2] before the rp2 loop; V stays in-loop.
//  - everything else verbatim R20: 128-row block, 1024 thr (16 waves),
//    128KB LDS, 512 blocks XCD-swizzled, cvt_pk, folded 0.125 scale,
//    guarded weight prefetch, fused prep_weights.

#define DQ 512
#define DC 768
#define MCTX 77
#define MPAD 96
#define DH 64
#define ROWS 128

typedef __attribute__((ext_vector_type(8))) short bf16x8;
typedef __attribute__((ext_vector_type(4))) short s16x4;
typedef __attribute__((ext_vector_type(4))) float f32x4;
typedef __attribute__((ext_vector_type(16))) float f32x16;

__device__ __forceinline__ short f2bf(float f) {
    unsigned u = __builtin_bit_cast(unsigned, f);
    u = (u + 0x7FFFu + ((u >> 16) & 1u)) >> 16;
    return (short)u;
}
// packed f32 pair -> bf16 pair (lo in bits[15:0]); RTNE, single VALU op
__device__ __forceinline__ unsigned cvtpk(float lo, float hi) {
    unsigned r;
    asm("v_cvt_pk_bf16_f32 %0, %1, %2" : "=v"(r) : "v"(lo), "v"(hi));
    return r;
}

#define SWZ(row, byte) ((byte) ^ (((row) & 7) << 4))
#define MFMA(a, b, c) __builtin_amdgcn_mfma_f32_16x16x32_bf16((a), (b), (c), 0, 0, 0)
#define MFMA32(a, b, c) __builtin_amdgcn_mfma_f32_32x32x16_bf16((a), (b), (c), 0, 0, 0)

// ---------------------------------------------------------------------------
// Fused weight prep (one launch):
//   blocks 0..127   : pack Wq -> WqF   (32x32x16-frag flat)
//   blocks 128..255 : pack Wo -> WoF
//   blocks 256..639 : transpose+cast Wk -> WkT [512][768]
//   blocks 640..1023: transpose+cast Wv -> WvT
// ---------------------------------------------------------------------------
__global__ void prep_weights(const float* __restrict__ Wq, const float* __restrict__ Wk,
                             const float* __restrict__ Wv, const float* __restrict__ Wo,
                             short* __restrict__ WqF, short* __restrict__ WkT,
                             short* __restrict__ WvT, short* __restrict__ WoF) {
    __shared__ float t[32][33];
    int bid = blockIdx.x;
    if (bid < 256) {
        // ---- pack_frag32: K=512, N=512 ----
        const float* src = (bid < 128) ? Wq : Wo;
        short* dst = (bid < 128) ? WqF : WoF;
        int vb = bid & 127;
        int idx = vb * 256 + threadIdx.x;
        int lane = idx & 63;
        int chunk = idx >> 6;
        int tt = chunk % 16, ks = chunk / 16;  // NT = 512>>5 = 16
        int n = tt * 32 + (lane & 31);
        int k0 = ks * 16 + (lane >> 5) * 8;
        bf16x8 v;
#pragma unroll
        for (int j = 0; j < 8; ++j) v[j] = f2bf(src[(size_t)(k0 + j) * 512 + n]);
        *(bf16x8*)(dst + (size_t)idx * 8) = v;
    } else {
        // ---- transpose_cast: K=768, N=512 ----
        const float* src = (bid < 640) ? Wk : Wv;
        short* dst = (bid < 640) ? WkT : WvT;
        int vb = (bid - 256) % 384;
        int tn = vb % 16, tk = vb / 16;  // ntn = 512>>5 = 16
        int tx = threadIdx.x & 31, ty = threadIdx.x >> 5;
#pragma unroll
        for (int i = 0; i < 32; i += 8)
            t[ty + i][tx] = src[(size_t)(tk * 32 + ty + i) * 512 + tn * 32 + tx];
        __syncthreads();
#pragma unroll
        for (int i = 0; i < 32; i += 8)
            dst[(size_t)(tn * 32 + ty + i) * 768 + tk * 32 + tx] = f2bf(t[tx][ty + i]);
    }
}

// ---------------------------------------------------------------------------
// K: Kb [16][96][512] ([b][ctx][dim], rows 77..95 zero)
// V: VbT [16][512][96] ([b][dim][ctx], ctx 77..95 zero)
// ---------------------------------------------------------------------------
__global__ __launch_bounds__(256, 1) void kv_proj(const float* __restrict__ ctxin,
                                                  const short* __restrict__ WkT,
                                                  const short* __restrict__ WvT,
                                                  short* __restrict__ Kb,
                                                  short* __restrict__ VbT) {
    int b = blockIdx.x >> 2;
    int kv = (blockIdx.x >> 1) & 1;
    int half = blockIdx.x & 1;
    const short* WT = kv ? WvT : WkT;

    __shared__ short A[48 * 768];
    const int tid = threadIdx.x;
    const int lane = tid & 63, wv = tid >> 6;
    const int l15 = lane & 15, l4 = lane >> 4;

#pragma unroll
    for (int it = 0; it < 36; ++it) {
        int id = it * 256 + tid;
        int row = id / 192, col = (id % 192) * 4;
        int gctx = half * 48 + row;
        float4 v = make_float4(0.f, 0.f, 0.f, 0.f);
        if (gctx < MCTX)
            v = ((const float4*)(ctxin + ((size_t)(b * MCTX + gctx)) * DC))[id % 192];
        s16x4 s4;
        s4[0] = f2bf(v.x); s4[1] = f2bf(v.y); s4[2] = f2bf(v.z); s4[3] = f2bf(v.w);
        *(s16x4*)((char*)A + row * 1536 + SWZ(row, col * 2)) = s4;
    }
    __syncthreads();

    f32x4 zf = {0.f, 0.f, 0.f, 0.f};
    f32x4 acc[3][8];
#pragma unroll
    for (int m = 0; m < 3; ++m)
#pragma unroll
        for (int nb = 0; nb < 8; ++nb) acc[m][nb] = zf;

    for (int ks = 0; ks < 24; ++ks) {
        bf16x8 bb[8], aa[3];
#pragma unroll
        for (int nb = 0; nb < 8; ++nb) {
            int n = wv * 128 + nb * 16 + l15;
            bb[nb] = *(const bf16x8*)((const char*)WT + (size_t)n * 1536 + ks * 64 + l4 * 16);
        }
#pragma unroll
        for (int m = 0; m < 3; ++m) {
            int row = m * 16 + l15;
            aa[m] = *(const bf16x8*)((char*)A + row * 1536 + SWZ(row, ks * 64 + l4 * 16));
        }
#pragma unroll
        for (int nb = 0; nb < 8; ++nb)
#pragma unroll
            for (int m = 0; m < 3; ++m) acc[m][nb] = MFMA(aa[m], bb[nb], acc[m][nb]);
    }

    if (kv == 0) {
#pragma unroll
        for (int m = 0; m < 3; ++m)
#pragma unroll
            for (int nb = 0; nb < 8; ++nb)
#pragma unroll
                for (int r = 0; r < 4; ++r) {
                    int ctxi = half * 48 + m * 16 + l4 * 4 + r;
                    int col = wv * 128 + nb * 16 + l15;
                    Kb[((size_t)(b * MPAD + ctxi)) * 512 + col] = f2bf(acc[m][nb][r]);
                }
    } else {
#pragma unroll
        for (int m = 0; m < 3; ++m)
#pragma unroll
            for (int nb = 0; nb < 8; ++nb)
#pragma unroll
                for (int r = 0; r < 4; ++r) {
                    int ctxi = half * 48 + m * 16 + l4 * 4 + r;
                    int col = wv * 128 + nb * 16 + l15;
                    VbT[((size_t)(b * 512 + col)) * MPAD + ctxi] = f2bf(acc[m][nb][r]);
                }
    }
}

// ---------------------------------------------------------------------------
// Fused: LN -> Qproj (32x32, swapped) -> attention (16x16, swapped PV)
//        -> Oproj (32x32, direct) + epilogue
// grid: 512 blocks (XCD-swizzled), 1024 threads (16 waves), 128 rows/block
// ---------------------------------------------------------------------------
__global__ __launch_bounds__(1024, 4) void fused_attn(
    const float* __restrict__ x, const float* __restrict__ gamma,
    const float* __restrict__ beta, const short* __restrict__ WqF,
    const short* __restrict__ WoF, const short* __restrict__ Kb,
    const short* __restrict__ VbT, const float* __restrict__ bo,
    float* __restrict__ out) {
    __shared__ short A[ROWS * 512];  // 128KB: h -> q -> AO, rows 1024B, XOR swizzled

    const int tid = threadIdx.x;
    const int lane = tid & 63, w16 = tid >> 6;  // w16 in 0..15
    const int l15 = lane & 15, l4 = lane >> 4;
    const int l31 = lane & 31, hi5 = lane >> 5;
    const int swz = (blockIdx.x & 7) * 64 + (blockIdx.x >> 3);  // XCD-chunked, 512%8==0
    const int b = swz >> 5;  // 32 blocks per batch element (4096/128)
    const size_t rowbase = (size_t)swz * ROWS;

    // ---- Phase 0: LayerNorm -> h bf16 in A (8 rows/wave, 4-row load batches) ----
    {
        float g[8], be[8];
        float4 g0 = ((const float4*)gamma)[lane * 2], g1 = ((const float4*)gamma)[lane * 2 + 1];
        float4 b0 = ((const float4*)beta)[lane * 2], b1 = ((const float4*)beta)[lane * 2 + 1];
        g[0] = g0.x; g[1] = g0.y; g[2] = g0.z; g[3] = g0.w;
        g[4] = g1.x; g[5] = g1.y; g[6] = g1.z; g[7] = g1.w;
        be[0] = b0.x; be[1] = b0.y; be[2] = b0.z; be[3] = b0.w;
        be[4] = b1.x; be[5] = b1.y; be[6] = b1.z; be[7] = b1.w;
#pragma unroll 1
        for (int g4 = 0; g4 < 2; ++g4) {
            float4 v0[4], v1[4];
#pragma unroll
            for (int j = 0; j < 4; ++j) {
                int row = w16 * 8 + g4 * 4 + j;
                const float4* xp = (const float4*)(x + (rowbase + row) * DQ);
                v0[j] = xp[lane * 2];
                v1[j] = xp[lane * 2 + 1];
            }
#pragma unroll
            for (int j = 0; j < 4; ++j) {
                int row = w16 * 8 + g4 * 4 + j;
                float vv[8] = {v0[j].x, v0[j].y, v0[j].z, v0[j].w,
                               v1[j].x, v1[j].y, v1[j].z, v1[j].w};
                float s = 0.f, s2 = 0.f;
#pragma unroll
                for (int i = 0; i < 8; ++i) { s += vv[i]; s2 = fmaf(vv[i], vv[i], s2); }
#pragma unroll
                for (int m = 1; m < 64; m <<= 1) {
                    s += __shfl_xor(s, m);
                    s2 += __shfl_xor(s2, m);
                }
                float mu = s * (1.f / 512.f);
                float var = s2 * (1.f / 512.f) - mu * mu;
                float rs = rsqrtf(var + 1e-5f);
                float hn[8];
#pragma unroll
                for (int i = 0; i < 8; ++i) hn[i] = (vv[i] - mu) * rs * g[i] + be[i];
                uint4 hv = make_uint4(cvtpk(hn[0], hn[1]), cvtpk(hn[2], hn[3]),
                                      cvtpk(hn[4], hn[5]), cvtpk(hn[6], hn[7]));
                *(uint4*)((char*)A + row * 1024 + SWZ(row, lane * 16)) = hv;
            }
        }
    }

    f32x4 zf = {0.f, 0.f, 0.f, 0.f};

// single 32-col weight tile (tile index = w16), K-slice ks
#define LDWF1(dst, W, ks)                                                                  \
    (dst) = *(const bf16x8*)((W) + (size_t)((((ks)*16 + w16) * 64 + lane)) * 8);
// A-tile 4x32-row frag read: rows nt*32+l31, k-bytes ks*32 + hi5*16
#define LDT128(dst, ks)                                                                    \
    _Pragma("unroll") for (int nt = 0; nt < 4; ++nt) {                                     \
        int row = nt * 32 + l31;                                                           \
        (dst)[nt] = *(const bf16x8*)((char*)A + row * 1024 +                               \
                                     SWZ(row, (ks)*32 + hi5 * 16));                        \
    }
// K-slice step, SWAPPED orientation (phase 1): ACC[nt] += W * h[nt]
#define GSTEP_Q(W, ACC, WBASE, kk)                                                         \
    {                                                                                      \
        bf16x8 hb[4];                                                                      \
        LDT128(hb, (kk));                                                                  \
        _Pragma("unroll") for (int nt = 0; nt < 4; ++nt)                                   \
            ACC[nt] = MFMA32((W), hb[nt], ACC[nt]);                                        \
        LDWF1((W), (WBASE), (kk) + 4);                                                     \
    }
#define GSTEP_Q_NR(W, ACC, kk)                                                             \
    {                                                                                      \
        bf16x8 hb[4];                                                                      \
        LDT128(hb, (kk));                                                                  \
        _Pragma("unroll") for (int nt = 0; nt < 4; ++nt)                                   \
            ACC[nt] = MFMA32((W), hb[nt], ACC[nt]);                                        \
    }
// K-slice step, DIRECT orientation (phase 3): ACC[mt] += AO[mt] * W
#define GSTEP_O(W, ACC, WBASE, kk)                                                         \
    {                                                                                      \
        bf16x8 hb[4];                                                                      \
        LDT128(hb, (kk));                                                                  \
        _Pragma("unroll") for (int mt = 0; mt < 4; ++mt)                                   \
            ACC[mt] = MFMA32(hb[mt], (W), ACC[mt]);                                        \
        LDWF1((W), (WBASE), (kk) + 4);                                                     \
    }
#define GSTEP_O_NR(W, ACC, kk)                                                             \
    {                                                                                      \
        bf16x8 hb[4];                                                                      \
        LDT128(hb, (kk));                                                                  \
        _Pragma("unroll") for (int mt = 0; mt < 4; ++mt)                                   \
            ACC[mt] = MFMA32(hb[mt], (W), ACC[mt]);                                        \
    }

    // ---- Phase 1: Q = h @ Wq via swapped 32x32: D = mfma(WqPack, h^T) = q^T ----
    {
        bf16x8 w0, w1, w2, w3;
        LDWF1(w0, WqF, 0);  // 4-deep prefetch issued before the barrier
        LDWF1(w1, WqF, 1);
        LDWF1(w2, WqF, 2);
        LDWF1(w3, WqF, 3);
        __syncthreads();   // h complete

        f32x16 qa[4];  // [nt = q-row tile]; wave owns q-col tile w16
#pragma unroll
        for (int nt = 0; nt < 4; ++nt)
#pragma unroll
            for (int i = 0; i < 16; ++i) qa[nt][i] = 0.f;

#pragma unroll 1
        for (int ks = 0; ks < 28; ks += 4) {  // refills target slices 4..31
            GSTEP_Q(w0, qa, WqF, ks)
            GSTEP_Q(w1, qa, WqF, ks + 1)
            GSTEP_Q(w2, qa, WqF, ks + 2)
            GSTEP_Q(w3, qa, WqF, ks + 3)
        }
        GSTEP_Q_NR(w0, qa, 28)  // last 4 slices: no refill, no over-read
        GSTEP_Q_NR(w1, qa, 29)
        GSTEP_Q_NR(w2, qa, 30)
        GSTEP_Q_NR(w3, qa, 31)
        __syncthreads();  // all waves done reading h

        // q writeback (0.125 QK scale folded in): lane = q-row, regs = q-cols
#pragma unroll
        for (int nt = 0; nt < 4; ++nt)
#pragma unroll
            for (int g = 0; g < 4; ++g) {
                uint2 qv = make_uint2(
                    cvtpk(qa[nt][g * 4] * 0.125f, qa[nt][g * 4 + 1] * 0.125f),
                    cvtpk(qa[nt][g * 4 + 2] * 0.125f, qa[nt][g * 4 + 3] * 0.125f));
                int row = nt * 32 + l31;
                int colb = (w16 * 32 + 8 * g + 4 * hi5) * 2;
                *(uint2*)((char*)A + row * 1024 + SWZ(row, colb)) = qv;
            }
        __syncthreads();  // q complete: attn waves read q cols written by other waves
    }

    // ---- Phase 2: attention; head = w16&7, row-half = w16>>3 (rp base) ----
    {
        const int cb = (w16 & 7) * 64;      // head's 64 q/V dims
        const int rpb = (w16 >> 3) * 4;     // rows rpb*16 .. rpb*16+63
        const int srcA = ((l4 & 1) << 5) + l15;
        const int srcB = srcA + 16;
        const bool hi = (l4 >> 1) != 0;

        // K fragments are rp-invariant: hoist out of the rp loop (10 frags,
        // 40 VGPRs; R20's P2 ran at 64/128 regs -> fits). Cuts 30 redundant
        // L2 loads per wave off the QK critical path.
        bf16x8 kR[5][2];
#pragma unroll
        for (int f = 0; f < 5; ++f) {
            kR[f][0] = *(const bf16x8*)(Kb + ((size_t)(b * MPAD + f * 16 + l15)) * 512 +
                                        cb + l4 * 8);
            kR[f][1] = *(const bf16x8*)(Kb + ((size_t)(b * MPAD + f * 16 + l15)) * 512 +
                                        cb + 32 + l4 * 8);
        }

        // P3 weight prefetch: issue now, lands during attention
        bf16x8 wo0, wo1, wo2, wo3;
        LDWF1(wo0, WoF, 0);
        LDWF1(wo1, WoF, 1);
        LDWF1(wo2, WoF, 2);
        LDWF1(wo3, WoF, 3);

#pragma unroll 1
        for (int rp2 = 0; rp2 < 4; ++rp2) {
            const int rp = rpb + rp2;
            bf16x8 qf0, qf1;
            {
                int qrow = rp * 16 + l15;
                qf0 = *(const bf16x8*)((char*)A + qrow * 1024 + SWZ(qrow, cb * 2 + l4 * 16));
                qf1 = *(const bf16x8*)((char*)A + qrow * 1024 + SWZ(qrow, cb * 2 + 64 + l4 * 16));
            }
            f32x4 sc[5];
            __builtin_amdgcn_s_setprio(1);
#pragma unroll
            for (int f = 0; f < 5; ++f) {
                sc[f] = MFMA(kR[f][0], qf0, zf);
                sc[f] = MFMA(kR[f][1], qf1, sc[f]);
            }
            __builtin_amdgcn_s_setprio(0);
            // q was pre-scaled by 0.125 at writeback; scores are final here
            float m = -1e30f;
#pragma unroll
            for (int f = 0; f < 5; ++f)
#pragma unroll
                for (int r = 0; r < 4; ++r) {
                    float v = sc[f][r];
                    if (f == 4 && (64 + l4 * 4 + r) >= MCTX) v = -1e30f;
                    sc[f][r] = v;
                    m = fmaxf(m, v);
                }
            m = fmaxf(m, __shfl_xor(m, 16));
            m = fmaxf(m, __shfl_xor(m, 32));
            float s = 0.f;
#pragma unroll
            for (int f = 0; f < 5; ++f)
#pragma unroll
                for (int r = 0; r < 4; ++r) {
                    float p = __expf(sc[f][r] - m);
                    sc[f][r] = p;
                    s += p;
                }
            s += __shfl_xor(s, 16);
            s += __shfl_xor(s, 32);
            float inv = 1.f / s;
            unsigned pk[6][2];
#pragma unroll
            for (int f = 0; f < 5; ++f) {
                pk[f][0] = cvtpk(sc[f][0] * inv, sc[f][1] * inv);
                pk[f][1] = cvtpk(sc[f][2] * inv, sc[f][3] * inv);
            }
            pk[5][0] = 0; pk[5][1] = 0;

            // PV swapped, per-ks interleave: only 4 pa regs live at a time.
            // D = mfma(A=V^T frag, B=P frag) = (PV)^T
            // lane = q-row (l15), regs r = consecutive dims (nb*16 + l4*4 + r)
            f32x4 ov[4];
#pragma unroll
            for (int nb = 0; nb < 4; ++nb) ov[nb] = zf;
#pragma unroll
            for (int ks = 0; ks < 3; ++ks) {
                unsigned aL0 = __shfl((int)pk[2 * ks][0], srcA);
                unsigned aL1 = __shfl((int)pk[2 * ks][1], srcA);
                unsigned aH0 = __shfl((int)pk[2 * ks + 1][0], srcA);
                unsigned aH1 = __shfl((int)pk[2 * ks + 1][1], srcA);
                unsigned bL0 = __shfl((int)pk[2 * ks][0], srcB);
                unsigned bL1 = __shfl((int)pk[2 * ks][1], srcB);
                unsigned bH0 = __shfl((int)pk[2 * ks + 1][0], srcB);
                unsigned bH1 = __shfl((int)pk[2 * ks + 1][1], srcB);
                unsigned paw[4];
                paw[0] = hi ? aH0 : aL0;
                paw[1] = hi ? aH1 : aL1;
                paw[2] = hi ? bH0 : bL0;
                paw[3] = hi ? bH1 : bL1;
                bf16x8 ap = __builtin_bit_cast(bf16x8, paw);
                __builtin_amdgcn_s_setprio(1);
#pragma unroll
                for (int nb = 0; nb < 4; ++nb) {
                    bf16x8 bv = *(const bf16x8*)(VbT +
                                                 ((size_t)(b * 512 + cb + nb * 16 + l15)) * MPAD +
                                                 ks * 32 + l4 * 8);
                    ov[nb] = MFMA(bv, ap, ov[nb]);  // swapped args
                }
                __builtin_amdgcn_s_setprio(0);
            }
            // AO writeback: vector b64, row = q-row, 4 consecutive dim cols
#pragma unroll
            for (int nb = 0; nb < 4; ++nb) {
                uint2 av = make_uint2(cvtpk(ov[nb][0], ov[nb][1]),
                                      cvtpk(ov[nb][2], ov[nb][3]));
                int row = rp * 16 + l15;
                int colb = (cb + nb * 16 + l4 * 4) * 2;
                *(uint2*)((char*)A + row * 1024 + SWZ(row, colb)) = av;
            }
        }

        // ---- Phase 3: O-proj 32x32 (K=512, direct) + residual + bias ----
        __syncthreads();  // AO complete across all waves (wo0..wo3 landed long ago)

        f32x16 oa[4];  // [mt = row tile]; wave owns out-col tile w16
#pragma unroll
        for (int mt = 0; mt < 4; ++mt)
#pragma unroll
            for (int i = 0; i < 16; ++i) oa[mt][i] = 0.f;

#pragma unroll 1
        for (int ks = 0; ks < 28; ks += 4) {  // refills target slices 4..31
            GSTEP_O(wo0, oa, WoF, ks)
            GSTEP_O(wo1, oa, WoF, ks + 1)
            GSTEP_O(wo2, oa, WoF, ks + 2)
            GSTEP_O(wo3, oa, WoF, ks + 3)
        }
        GSTEP_O_NR(wo0, oa, 28)  // last 4 slices: no refill, no over-read
        GSTEP_O_NR(wo1, oa, 29)
        GSTEP_O_NR(wo2, oa, 30)
        GSTEP_O_NR(wo3, oa, 31)

        // epilogue: out = x + oa + bo; lane = out-col (coalesced), regs = rows
        {
            int col = w16 * 32 + l31;
            float bov = bo[col];
#pragma unroll
            for (int mt = 0; mt < 4; ++mt) {
                float xv[16];
#pragma unroll
                for (int rg = 0; rg < 16; ++rg) {
                    int row = mt * 32 + (rg & 3) + 8 * (rg >> 2) + 4 * hi5;
                    xv[rg] = x[(rowbase + row) * DQ + col];
                }
#pragma unroll
                for (int rg = 0; rg < 16; ++rg) {
                    int row = mt * 32 + (rg & 3) + 8 * (rg >> 2) + 4 * hi5;
                    size_t gi = (rowbase + row) * DQ + col;
                    out[gi] = xv[rg] + oa[mt][rg] + bov;
                }
            }
        }
    }
}

// ---------------------------------------------------------------------------
extern "C" void kernel_launch(void* const* d_in, const int* in_sizes, int n_in,
                              void* d_out, int out_size, void* d_ws, size_t ws_size,
                              hipStream_t stream) {
    const float* x = (const float*)d_in[0];
    const float* ctx = (const float*)d_in[1];
    const float* gamma = (const float*)d_in[2];
    const float* beta = (const float*)d_in[3];
    const float* Wq = (const float*)d_in[4];
    const float* Wk = (const float*)d_in[5];
    const float* Wv = (const float*)d_in[6];
    const float* Wo = (const float*)d_in[7];
    const float* bo = (const float*)d_in[8];
    float* out = (float*)d_out;

    char* ws = (char*)d_ws;
    short* WqF = (short*)(ws + 0);        // 32x32-frag flat bf16 [32ks][16t][64lane][8]
    short* WkT = (short*)(ws + 524288);   // [512][768] row-major W^T
    short* WvT = (short*)(ws + 1310720);  // [512][768]
    short* WoF = (short*)(ws + 2097152);  // 32x32-frag flat
    short* Kb = (short*)(ws + 2621440);   // [16][96][512]  K: [b][ctx][dim]
    short* VbT = (short*)(ws + 4194304);  // [16][512][96]  V: [b][dim][ctx]

    prep_weights<<<1024, 256, 0, stream>>>(Wq, Wk, Wv, Wo, WqF, WkT, WvT, WoF);
    kv_proj<<<64, 256, 0, stream>>>(ctx, WkT, WvT, Kb, VbT);
    fused_attn<<<512, 1024, 0, stream>>>(x, gamma, beta, WqF, WoF, Kb, VbT, bo, out);
}

// Round 9
// 187.811 us; speedup vs baseline: 1.2453x; 1.0204x over previous
//
#include <hip/hip_runtime.h>

// CrossAttention fused kernel for MI355X (gfx950) — R23
// R23 = consolidation: R18's fused_attn (fastest measured, 175us) verbatim
//       + R19's fused prep_weights (3 launches, lowest overhead).
//  - R22 post-mortem: K-hoist null, VGPR stayed 64 (compiler folded it);
//    P2 load-issue confirmed non-limiting. Evidence table across R18-R22:
//    fused_attn best at 64-row + V-hoist (175) but was paired with 6 launches;
//    128-row cut overhead but slowed fused (+10us, conflicts 6.8M->11M).
//  - This round pairs min-fused with min-overhead. No new mechanisms.

#define DQ 512
#define DC 768
#define MCTX 77
#define MPAD 96
#define DH 64

typedef __attribute__((ext_vector_type(8))) short bf16x8;
typedef __attribute__((ext_vector_type(4))) short s16x4;
typedef __attribute__((ext_vector_type(4))) float f32x4;
typedef __attribute__((ext_vector_type(16))) float f32x16;

__device__ __forceinline__ short f2bf(float f) {
    unsigned u = __builtin_bit_cast(unsigned, f);
    u = (u + 0x7FFFu + ((u >> 16) & 1u)) >> 16;
    return (short)u;
}
// packed f32 pair -> bf16 pair (lo in bits[15:0]); RTNE, single VALU op
__device__ __forceinline__ unsigned cvtpk(float lo, float hi) {
    unsigned r;
    asm("v_cvt_pk_bf16_f32 %0, %1, %2" : "=v"(r) : "v"(lo), "v"(hi));
    return r;
}

#define SWZ(row, byte) ((byte) ^ (((row) & 7) << 4))
#define MFMA(a, b, c) __builtin_amdgcn_mfma_f32_16x16x32_bf16((a), (b), (c), 0, 0, 0)
#define MFMA32(a, b, c) __builtin_amdgcn_mfma_f32_32x32x16_bf16((a), (b), (c), 0, 0, 0)

// ---------------------------------------------------------------------------
// Fused weight prep (one launch):
//   blocks 0..127   : pack Wq -> WqF   (32x32x16-frag flat)
//   blocks 128..255 : pack Wo -> WoF
//   blocks 256..639 : transpose+cast Wk -> WkT [512][768]
//   blocks 640..1023: transpose+cast Wv -> WvT
// ---------------------------------------------------------------------------
__global__ void prep_weights(const float* __restrict__ Wq, const float* __restrict__ Wk,
                             const float* __restrict__ Wv, const float* __restrict__ Wo,
                             short* __restrict__ WqF, short* __restrict__ WkT,
                             short* __restrict__ WvT, short* __restrict__ WoF) {
    __shared__ float t[32][33];
    int bid = blockIdx.x;
    if (bid < 256) {
        // ---- pack_frag32: K=512, N=512 ----
        const float* src = (bid < 128) ? Wq : Wo;
        short* dst = (bid < 128) ? WqF : WoF;
        int vb = bid & 127;
        int idx = vb * 256 + threadIdx.x;
        int lane = idx & 63;
        int chunk = idx >> 6;
        int tt = chunk % 16, ks = chunk / 16;  // NT = 512>>5 = 16
        int n = tt * 32 + (lane & 31);
        int k0 = ks * 16 + (lane >> 5) * 8;
        bf16x8 v;
#pragma unroll
        for (int j = 0; j < 8; ++j) v[j] = f2bf(src[(size_t)(k0 + j) * 512 + n]);
        *(bf16x8*)(dst + (size_t)idx * 8) = v;
    } else {
        // ---- transpose_cast: K=768, N=512 ----
        const float* src = (bid < 640) ? Wk : Wv;
        short* dst = (bid < 640) ? WkT : WvT;
        int vb = (bid - 256) % 384;
        int tn = vb % 16, tk = vb / 16;  // ntn = 512>>5 = 16
        int tx = threadIdx.x & 31, ty = threadIdx.x >> 5;
#pragma unroll
        for (int i = 0; i < 32; i += 8)
            t[ty + i][tx] = src[(size_t)(tk * 32 + ty + i) * 512 + tn * 32 + tx];
        __syncthreads();
#pragma unroll
        for (int i = 0; i < 32; i += 8)
            dst[(size_t)(tn * 32 + ty + i) * 768 + tk * 32 + tx] = f2bf(t[tx][ty + i]);
    }
}

// ---------------------------------------------------------------------------
// K: Kb [16][96][512] ([b][ctx][dim], rows 77..95 zero)
// V: VbT [16][512][96] ([b][dim][ctx], ctx 77..95 zero)
// ---------------------------------------------------------------------------
__global__ __launch_bounds__(256, 1) void kv_proj(const float* __restrict__ ctxin,
                                                  const short* __restrict__ WkT,
                                                  const short* __restrict__ WvT,
                                                  short* __restrict__ Kb,
                                                  short* __restrict__ VbT) {
    int b = blockIdx.x >> 2;
    int kv = (blockIdx.x >> 1) & 1;
    int half = blockIdx.x & 1;
    const short* WT = kv ? WvT : WkT;

    __shared__ short A[48 * 768];
    const int tid = threadIdx.x;
    const int lane = tid & 63, wv = tid >> 6;
    const int l15 = lane & 15, l4 = lane >> 4;

#pragma unroll
    for (int it = 0; it < 36; ++it) {
        int id = it * 256 + tid;
        int row = id / 192, col = (id % 192) * 4;
        int gctx = half * 48 + row;
        float4 v = make_float4(0.f, 0.f, 0.f, 0.f);
        if (gctx < MCTX)
            v = ((const float4*)(ctxin + ((size_t)(b * MCTX + gctx)) * DC))[id % 192];
        s16x4 s4;
        s4[0] = f2bf(v.x); s4[1] = f2bf(v.y); s4[2] = f2bf(v.z); s4[3] = f2bf(v.w);
        *(s16x4*)((char*)A + row * 1536 + SWZ(row, col * 2)) = s4;
    }
    __syncthreads();

    f32x4 zf = {0.f, 0.f, 0.f, 0.f};
    f32x4 acc[3][8];
#pragma unroll
    for (int m = 0; m < 3; ++m)
#pragma unroll
        for (int nb = 0; nb < 8; ++nb) acc[m][nb] = zf;

    for (int ks = 0; ks < 24; ++ks) {
        bf16x8 bb[8], aa[3];
#pragma unroll
        for (int nb = 0; nb < 8; ++nb) {
            int n = wv * 128 + nb * 16 + l15;
            bb[nb] = *(const bf16x8*)((const char*)WT + (size_t)n * 1536 + ks * 64 + l4 * 16);
        }
#pragma unroll
        for (int m = 0; m < 3; ++m) {
            int row = m * 16 + l15;
            aa[m] = *(const bf16x8*)((char*)A + row * 1536 + SWZ(row, ks * 64 + l4 * 16));
        }
#pragma unroll
        for (int nb = 0; nb < 8; ++nb)
#pragma unroll
            for (int m = 0; m < 3; ++m) acc[m][nb] = MFMA(aa[m], bb[nb], acc[m][nb]);
    }

    if (kv == 0) {
#pragma unroll
        for (int m = 0; m < 3; ++m)
#pragma unroll
            for (int nb = 0; nb < 8; ++nb)
#pragma unroll
                for (int r = 0; r < 4; ++r) {
                    int ctxi = half * 48 + m * 16 + l4 * 4 + r;
                    int col = wv * 128 + nb * 16 + l15;
                    Kb[((size_t)(b * MPAD + ctxi)) * 512 + col] = f2bf(acc[m][nb][r]);
                }
    } else {
#pragma unroll
        for (int m = 0; m < 3; ++m)
#pragma unroll
            for (int nb = 0; nb < 8; ++nb)
#pragma unroll
                for (int r = 0; r < 4; ++r) {
                    int ctxi = half * 48 + m * 16 + l4 * 4 + r;
                    int col = wv * 128 + nb * 16 + l15;
                    VbT[((size_t)(b * 512 + col)) * MPAD + ctxi] = f2bf(acc[m][nb][r]);
                }
    }
}

// ---------------------------------------------------------------------------
// Fused: LN -> Qproj (32x32, swapped) -> attention (16x16, swapped PV)
//        -> Oproj (32x32, direct) + epilogue   [verbatim R18, fastest measured]
// grid: 1024 blocks (XCD-swizzled), 512 threads (8 waves), 64 rows/block
// ---------------------------------------------------------------------------
__global__ __launch_bounds__(512, 4) void fused_attn(
    const float* __restrict__ x, const float* __restrict__ gamma,
    const float* __restrict__ beta, const short* __restrict__ WqF,
    const short* __restrict__ WoF, const short* __restrict__ Kb,
    const short* __restrict__ VbT, const float* __restrict__ bo,
    float* __restrict__ out) {
    __shared__ short A[64 * 512];  // 64KB: h -> q -> AO, rows 1024B, XOR swizzled

    const int tid = threadIdx.x;
    const int lane = tid & 63, wv = tid >> 6;  // wv = head
    const int l15 = lane & 15, l4 = lane >> 4;
    const int l31 = lane & 31, hi5 = lane >> 5;
    const int swz = (blockIdx.x & 7) * 128 + (blockIdx.x >> 3);  // XCD-chunked
    const int b = swz >> 6;
    const size_t rowbase = (size_t)swz * 64;
    const int cb = wv * 64;  // this wave's 64 cols == head wv's dims

    // ---- Phase 0: LayerNorm -> h bf16 in A (8 rows/wave, 4-row load batches) ----
    {
        float g[8], be[8];
        float4 g0 = ((const float4*)gamma)[lane * 2], g1 = ((const float4*)gamma)[lane * 2 + 1];
        float4 b0 = ((const float4*)beta)[lane * 2], b1 = ((const float4*)beta)[lane * 2 + 1];
        g[0] = g0.x; g[1] = g0.y; g[2] = g0.z; g[3] = g0.w;
        g[4] = g1.x; g[5] = g1.y; g[6] = g1.z; g[7] = g1.w;
        be[0] = b0.x; be[1] = b0.y; be[2] = b0.z; be[3] = b0.w;
        be[4] = b1.x; be[5] = b1.y; be[6] = b1.z; be[7] = b1.w;
#pragma unroll 1
        for (int g4 = 0; g4 < 2; ++g4) {
            float4 v0[4], v1[4];
#pragma unroll
            for (int j = 0; j < 4; ++j) {
                int row = wv * 8 + g4 * 4 + j;
                const float4* xp = (const float4*)(x + (rowbase + row) * DQ);
                v0[j] = xp[lane * 2];
                v1[j] = xp[lane * 2 + 1];
            }
#pragma unroll
            for (int j = 0; j < 4; ++j) {
                int row = wv * 8 + g4 * 4 + j;
                float vv[8] = {v0[j].x, v0[j].y, v0[j].z, v0[j].w,
                               v1[j].x, v1[j].y, v1[j].z, v1[j].w};
                float s = 0.f, s2 = 0.f;
#pragma unroll
                for (int i = 0; i < 8; ++i) { s += vv[i]; s2 = fmaf(vv[i], vv[i], s2); }
#pragma unroll
                for (int m = 1; m < 64; m <<= 1) {
                    s += __shfl_xor(s, m);
                    s2 += __shfl_xor(s2, m);
                }
                float mu = s * (1.f / 512.f);
                float var = s2 * (1.f / 512.f) - mu * mu;
                float rs = rsqrtf(var + 1e-5f);
                float hn[8];
#pragma unroll
                for (int i = 0; i < 8; ++i) hn[i] = (vv[i] - mu) * rs * g[i] + be[i];
                uint4 hv = make_uint4(cvtpk(hn[0], hn[1]), cvtpk(hn[2], hn[3]),
                                      cvtpk(hn[4], hn[5]), cvtpk(hn[6], hn[7]));
                *(uint4*)((char*)A + row * 1024 + SWZ(row, lane * 16)) = hv;
            }
        }
    }

    f32x4 zf = {0.f, 0.f, 0.f, 0.f};

// flat 32x32-frag weight load: tile index wv*2+tt, K-slice ks
#define LDWF(dst, W, ks)                                                                   \
    _Pragma("unroll") for (int tt = 0; tt < 2; ++tt) {                                     \
        (dst)[tt] = *(const bf16x8*)((W) +                                                 \
            (size_t)((((ks)*16 + wv * 2 + tt) * 64 + lane)) * 8);                          \
    }
// A-tile 32-row frag read: rows tt*32+l31, k-bytes ks*32 + hi5*16
#define LDT32(dst, ks)                                                                     \
    _Pragma("unroll") for (int tt = 0; tt < 2; ++tt) {                                     \
        int row = tt * 32 + l31;                                                           \
        (dst)[tt] = *(const bf16x8*)((char*)A + row * 1024 +                               \
                                     SWZ(row, (ks)*32 + hi5 * 16));                        \
    }
// K-slice step, SWAPPED orientation (phase 1): ACC[mt][nt] += W[mt] * h[nt]
#define GSTEP_Q(W, ACC, WBASE, kk)                                                         \
    {                                                                                      \
        bf16x8 hb[2];                                                                      \
        LDT32(hb, (kk));                                                                   \
        _Pragma("unroll") for (int mt = 0; mt < 2; ++mt)                                   \
            _Pragma("unroll") for (int nt = 0; nt < 2; ++nt)                               \
                ACC[mt][nt] = MFMA32((W)[mt], hb[nt], ACC[mt][nt]);                        \
        LDWF((W), (WBASE), (kk) + 4);                                                      \
    }
#define GSTEP_Q_NR(W, ACC, kk)                                                             \
    {                                                                                      \
        bf16x8 hb[2];                                                                      \
        LDT32(hb, (kk));                                                                   \
        _Pragma("unroll") for (int mt = 0; mt < 2; ++mt)                                   \
            _Pragma("unroll") for (int nt = 0; nt < 2; ++nt)                               \
                ACC[mt][nt] = MFMA32((W)[mt], hb[nt], ACC[mt][nt]);                        \
    }
// K-slice step, DIRECT orientation (phase 3): ACC[mt][ct] += AO[mt] * W[ct]
#define GSTEP_O(W, ACC, WBASE, kk)                                                         \
    {                                                                                      \
        bf16x8 hb[2];                                                                      \
        LDT32(hb, (kk));                                                                   \
        _Pragma("unroll") for (int mt = 0; mt < 2; ++mt)                                   \
            _Pragma("unroll") for (int ct = 0; ct < 2; ++ct)                               \
                ACC[mt][ct] = MFMA32(hb[mt], (W)[ct], ACC[mt][ct]);                        \
        LDWF((W), (WBASE), (kk) + 4);                                                      \
    }
#define GSTEP_O_NR(W, ACC, kk)                                                             \
    {                                                                                      \
        bf16x8 hb[2];                                                                      \
        LDT32(hb, (kk));                                                                   \
        _Pragma("unroll") for (int mt = 0; mt < 2; ++mt)                                   \
            _Pragma("unroll") for (int ct = 0; ct < 2; ++ct)                               \
                ACC[mt][ct] = MFMA32(hb[mt], (W)[ct], ACC[mt][ct]);                        \
    }

    // ---- Phase 1: Q = h @ Wq via swapped 32x32: D = mfma(WqPack, h^T) = q^T ----
    {
        bf16x8 w0[2], w1[2], w2[2], w3[2];
        LDWF(w0, WqF, 0);  // 4-deep prefetch issued before the barrier
        LDWF(w1, WqF, 1);
        LDWF(w2, WqF, 2);
        LDWF(w3, WqF, 3);
        __syncthreads();   // h complete

        f32x16 qa[2][2];  // [mt=qcol tile][nt=qrow tile]
#pragma unroll
        for (int mt = 0; mt < 2; ++mt)
#pragma unroll
            for (int nt = 0; nt < 2; ++nt)
#pragma unroll
                for (int i = 0; i < 16; ++i) qa[mt][nt][i] = 0.f;

#pragma unroll 1
        for (int ks = 0; ks < 28; ks += 4) {  // refills target slices 4..31
            GSTEP_Q(w0, qa, WqF, ks)
            GSTEP_Q(w1, qa, WqF, ks + 1)
            GSTEP_Q(w2, qa, WqF, ks + 2)
            GSTEP_Q(w3, qa, WqF, ks + 3)
        }
        GSTEP_Q_NR(w0, qa, 28)  // last 4 slices: no refill, no over-read
        GSTEP_Q_NR(w1, qa, 29)
        GSTEP_Q_NR(w2, qa, 30)
        GSTEP_Q_NR(w3, qa, 31)
        __syncthreads();  // all waves done reading h

        // q writeback (0.125 QK scale folded in): lane = q-row, regs = q-cols
#pragma unroll
        for (int mt = 0; mt < 2; ++mt)
#pragma unroll
            for (int nt = 0; nt < 2; ++nt)
#pragma unroll
                for (int g = 0; g < 4; ++g) {
                    uint2 qv = make_uint2(
                        cvtpk(qa[mt][nt][g * 4] * 0.125f, qa[mt][nt][g * 4 + 1] * 0.125f),
                        cvtpk(qa[mt][nt][g * 4 + 2] * 0.125f, qa[mt][nt][g * 4 + 3] * 0.125f));
                    int row = nt * 32 + l31;
                    int colb = (cb + mt * 32 + 8 * g + 4 * hi5) * 2;
                    *(uint2*)((char*)A + row * 1024 + SWZ(row, colb)) = qv;
                }
        // no barrier: each wave reads only its own 64 columns from here
    }

    // ---- Phase 2: attention for head wv (16x16, swapped PV, P in regs) ----
    {
        const int srcA = ((l4 & 1) << 5) + l15;
        const int srcB = srcA + 16;
        const bool hi = (l4 >> 1) != 0;

        // V fragments are rp-invariant: hoist out of the rp loop (48 VGPRs);
        // loads issue here, first use is after rp0 softmax -> latency hidden
        bf16x8 vR[3][4];
#pragma unroll
        for (int ks = 0; ks < 3; ++ks)
#pragma unroll
            for (int nb = 0; nb < 4; ++nb)
                vR[ks][nb] = *(const bf16x8*)(VbT +
                                              ((size_t)(b * 512 + cb + nb * 16 + l15)) * MPAD +
                                              ks * 32 + l4 * 8);

#pragma unroll 1
        for (int rp = 0; rp < 4; ++rp) {
            bf16x8 qf0, qf1;
            {
                int qrow = rp * 16 + l15;
                qf0 = *(const bf16x8*)((char*)A + qrow * 1024 + SWZ(qrow, cb * 2 + l4 * 16));
                qf1 = *(const bf16x8*)((char*)A + qrow * 1024 + SWZ(qrow, cb * 2 + 64 + l4 * 16));
            }
            f32x4 sc[5];
            __builtin_amdgcn_s_setprio(1);
#pragma unroll
            for (int f = 0; f < 5; ++f) {
                bf16x8 k0 = *(const bf16x8*)(Kb + ((size_t)(b * MPAD + f * 16 + l15)) * 512 +
                                             cb + l4 * 8);
                bf16x8 k1 = *(const bf16x8*)(Kb + ((size_t)(b * MPAD + f * 16 + l15)) * 512 +
                                             cb + 32 + l4 * 8);
                sc[f] = MFMA(k0, qf0, zf);
                sc[f] = MFMA(k1, qf1, sc[f]);
            }
            __builtin_amdgcn_s_setprio(0);
            // q was pre-scaled by 0.125 at writeback; scores are final here
            float m = -1e30f;
#pragma unroll
            for (int f = 0; f < 5; ++f)
#pragma unroll
                for (int r = 0; r < 4; ++r) {
                    float v = sc[f][r];
                    if (f == 4 && (64 + l4 * 4 + r) >= MCTX) v = -1e30f;
                    sc[f][r] = v;
                    m = fmaxf(m, v);
                }
            m = fmaxf(m, __shfl_xor(m, 16));
            m = fmaxf(m, __shfl_xor(m, 32));
            float s = 0.f;
#pragma unroll
            for (int f = 0; f < 5; ++f)
#pragma unroll
                for (int r = 0; r < 4; ++r) {
                    float p = __expf(sc[f][r] - m);
                    sc[f][r] = p;
                    s += p;
                }
            s += __shfl_xor(s, 16);
            s += __shfl_xor(s, 32);
            float inv = 1.f / s;
            unsigned pk[6][2];
#pragma unroll
            for (int f = 0; f < 5; ++f) {
                pk[f][0] = cvtpk(sc[f][0] * inv, sc[f][1] * inv);
                pk[f][1] = cvtpk(sc[f][2] * inv, sc[f][3] * inv);
            }
            pk[5][0] = 0; pk[5][1] = 0;
            unsigned pa[3][4];
#pragma unroll
            for (int ks = 0; ks < 3; ++ks) {
                unsigned aL0 = __shfl((int)pk[2 * ks][0], srcA);
                unsigned aL1 = __shfl((int)pk[2 * ks][1], srcA);
                unsigned aH0 = __shfl((int)pk[2 * ks + 1][0], srcA);
                unsigned aH1 = __shfl((int)pk[2 * ks + 1][1], srcA);
                unsigned bL0 = __shfl((int)pk[2 * ks][0], srcB);
                unsigned bL1 = __shfl((int)pk[2 * ks][1], srcB);
                unsigned bH0 = __shfl((int)pk[2 * ks + 1][0], srcB);
                unsigned bH1 = __shfl((int)pk[2 * ks + 1][1], srcB);
                pa[ks][0] = hi ? aH0 : aL0;
                pa[ks][1] = hi ? aH1 : aL1;
                pa[ks][2] = hi ? bH0 : bL0;
                pa[ks][3] = hi ? bH1 : bL1;
            }
            // PV swapped: D = mfma(A=V^T frag, B=P frag) = (PV)^T
            // lane = q-row (l15), regs r = consecutive dims (nb*16 + l4*4 + r)
            f32x4 ov[4];
#pragma unroll
            for (int nb = 0; nb < 4; ++nb) ov[nb] = zf;
            __builtin_amdgcn_s_setprio(1);
#pragma unroll
            for (int ks = 0; ks < 3; ++ks) {
                bf16x8 ap = __builtin_bit_cast(bf16x8, pa[ks]);
#pragma unroll
                for (int nb = 0; nb < 4; ++nb) {
                    ov[nb] = MFMA(vR[ks][nb], ap, ov[nb]);  // swapped args, V in regs
                }
            }
            __builtin_amdgcn_s_setprio(0);
            // AO writeback: vector b64, row = q-row, 4 consecutive dim cols
#pragma unroll
            for (int nb = 0; nb < 4; ++nb) {
                uint2 av = make_uint2(cvtpk(ov[nb][0], ov[nb][1]),
                                      cvtpk(ov[nb][2], ov[nb][3]));
                int row = rp * 16 + l15;
                int colb = (cb + nb * 16 + l4 * 4) * 2;
                *(uint2*)((char*)A + row * 1024 + SWZ(row, colb)) = av;
            }
        }
    }

    // ---- Phase 3: O-proj 32x32 (K=512, direct) + residual + bias ----
    {
        bf16x8 w0[2], w1[2], w2[2], w3[2];
        LDWF(w0, WoF, 0);  // 4-deep prefetch issued before the barrier
        LDWF(w1, WoF, 1);
        LDWF(w2, WoF, 2);
        LDWF(w3, WoF, 3);
        __syncthreads();   // AO complete across all waves

        f32x16 oa[2][2];  // [mt=row tile][ct=col tile]
#pragma unroll
        for (int mt = 0; mt < 2; ++mt)
#pragma unroll
            for (int ct = 0; ct < 2; ++ct)
#pragma unroll
                for (int i = 0; i < 16; ++i) oa[mt][ct][i] = 0.f;

#pragma unroll 1
        for (int ks = 0; ks < 28; ks += 4) {  // refills target slices 4..31
            GSTEP_O(w0, oa, WoF, ks)
            GSTEP_O(w1, oa, WoF, ks + 1)
            GSTEP_O(w2, oa, WoF, ks + 2)
            GSTEP_O(w3, oa, WoF, ks + 3)
        }
        GSTEP_O_NR(w0, oa, 28)  // last 4 slices: no refill, no over-read
        GSTEP_O_NR(w1, oa, 29)
        GSTEP_O_NR(w2, oa, 30)
        GSTEP_O_NR(w3, oa, 31)

        // epilogue: out = x + oa + bo; lane = out-col (coalesced), regs = rows
#pragma unroll
        for (int mt = 0; mt < 2; ++mt)
#pragma unroll
            for (int ct = 0; ct < 2; ++ct) {
                int col = cb + ct * 32 + l31;
                float bov = bo[col];
                float xv[16];
#pragma unroll
                for (int rg = 0; rg < 16; ++rg) {
                    int row = mt * 32 + (rg & 3) + 8 * (rg >> 2) + 4 * hi5;
                    xv[rg] = x[(rowbase + row) * DQ + col];
                }
#pragma unroll
                for (int rg = 0; rg < 16; ++rg) {
                    int row = mt * 32 + (rg & 3) + 8 * (rg >> 2) + 4 * hi5;
                    size_t gi = (rowbase + row) * DQ + col;
                    out[gi] = xv[rg] + oa[mt][ct][rg] + bov;
                }
            }
    }
}

// ---------------------------------------------------------------------------
extern "C" void kernel_launch(void* const* d_in, const int* in_sizes, int n_in,
                              void* d_out, int out_size, void* d_ws, size_t ws_size,
                              hipStream_t stream) {
    const float* x = (const float*)d_in[0];
    const float* ctx = (const float*)d_in[1];
    const float* gamma = (const float*)d_in[2];
    const float* beta = (const float*)d_in[3];
    const float* Wq = (const float*)d_in[4];
    const float* Wk = (const float*)d_in[5];
    const float* Wv = (const float*)d_in[6];
    const float* Wo = (const float*)d_in[7];
    const float* bo = (const float*)d_in[8];
    float* out = (float*)d_out;

    char* ws = (char*)d_ws;
    short* WqF = (short*)(ws + 0);        // 32x32-frag flat bf16 [32ks][16t][64lane][8]
    short* WkT = (short*)(ws + 524288);   // [512][768] row-major W^T
    short* WvT = (short*)(ws + 1310720);  // [512][768]
    short* WoF = (short*)(ws + 2097152);  // 32x32-frag flat
    short* Kb = (short*)(ws + 2621440);   // [16][96][512]  K: [b][ctx][dim]
    short* VbT = (short*)(ws + 4194304);  // [16][512][96]  V: [b][dim][ctx]

    prep_weights<<<1024, 256, 0, stream>>>(Wq, Wk, Wv, Wo, WqF, WkT, WvT, WoF);
    kv_proj<<<64, 256, 0, stream>>>(ctx, WkT, WvT, Kb, VbT);
    fused_attn<<<1024, 512, 0, stream>>>(x, gamma, beta, WqF, WoF, Kb, VbT, bo, out);
}